// Round 8
// baseline (56.098 us; speedup 1.0000x reference)
//
#include <hip/hip_runtime.h>
#include <math.h>

// LearnableHighpass biquad, B=64, T=524288, fp32.
// Chunked-parallel IIR (128-sample zero-state warm-up, pole^128 ~ 3e-7).
// R8 = R7 (LDS wave-local transpose, fully coalesced global access,
// counted-vmcnt pipeline) with LT 512 -> 256: grid 1024 -> 2048 waves,
// 4 -> 6 waves/CU (LDS-capped), attacking the latency-bound profile
// (R7: 2.5 TB/s HBM, VALUBusy 8%, occ 9% at 1 wave/SIMD).
// Read redundancy 1.5x logical is L2/L3-deduped (R7: FETCH 82MB << 160MB).

typedef float f4 __attribute__((ext_vector_type(4)));

namespace {
constexpr int T_LEN = 524288;
constexpr int B_ROWS = 64;
constexpr int LT = 256;                 // samples per chunk (per lane)
constexpr int WU = 128;                 // warm-up samples
constexpr int CPR = T_LEN / LT;         // 2048 chunks per row
constexpr int NV = T_LEN / 4;           // 131072 f4 vectors per row
constexpr int STRIDEV = LT / 4;         // 64 vectors chunk stride
constexpr int ITERS = (WU + LT) / 32;   // 12 stages of 32 samples
constexpr int SKIP = WU / 32;           // 4 warm-up stages (no store)
}

using gfp = const float __attribute__((address_space(1)))*;
using lfp = float __attribute__((address_space(3)))*;

__global__ __launch_bounds__(64) void hp_biquad(
    const float* __restrict__ x,
    const float* __restrict__ ffreq,
    const float* __restrict__ fqv,
    const int*  __restrict__ srv,
    float* __restrict__ y)
{
    // stage buffers: in double-buffered (2x8KB), out single (8KB) = 24 KB
    __shared__ f4 inb[2][512];
    __shared__ f4 outb[512];

    const float fsr   = (float)srv[0];
    const float w0    = 6.28318530717958647692f * ffreq[0] / fsr;
    const float sw    = sinf(w0);
    const float cw    = cosf(w0);
    const float alpha = sw / (2.0f * fqv[0]);
    const float ia0   = 1.0f / (1.0f + alpha);
    const float b0 = 0.5f * (1.0f + cw) * ia0;
    const float b1 = -(1.0f + cw) * ia0;
    const float b2 = b0;
    const float a1 = -2.0f * cw * ia0;
    const float a2 = (1.0f - alpha) * ia0;

    const int lane = threadIdx.x;               // 0..63 == chunk-lane
    const int wv   = blockIdx.x;                // wave id, 0..2047
    const int c0   = wv * 64;                   // first chunk of this wave
    const int row  = c0 / CPR;
    const int c0r  = c0 & (CPR - 1);
    const bool firstWave  = (c0r == 0);
    const int rowBaseVec  = row * NV;
    const int waveVecBase = rowBaseVec + c0r * STRIDEV - WU / 4;

    // coop call j, lane m covers chunk-lane L = 8j + (m>>3), vector
    // V = (m&7) ^ ((m>>3)&7); 8 lanes cover one contiguous 128 B segment.
    // LDS slot j*64+m <- that vector (linear dst required by global_load_lds);
    // lane l's private vector v sits in slot (l<<3) + (v ^ (l&7)).
    const int vstar   = (lane & 7) ^ ((lane >> 3) & 7);
    const int laneOff = (lane >> 3) * STRIDEV + vstar;

    const f4* __restrict__ xv = (const f4*)x;
    f4* __restrict__ yv       = (f4*)y;

    auto issue_loads = [&](int k, int bufi) {
        const int base  = waveVecBase + 8 * k + laneOff;
        const bool clmp = firstWave && (k < SKIP);   // wave-uniform
#pragma unroll
        for (int j = 0; j < 8; ++j) {
            int idx = base + j * (8 * STRIDEV);
            if (clmp) idx = idx < rowBaseVec ? rowBaseVec : idx;  // zeroed later
            __builtin_amdgcn_global_load_lds(
                (gfp)(const float*)(xv + idx),
                (lfp)(float*)(&inb[bufi][j * 64]), 16, 0, 0);
        }
    };

    float xm1 = 0.f, xm2 = 0.f, ym1 = 0.f, ym2 = 0.f;
    auto step = [&](float xt) -> float {
        float t  = b0 * xt + b1 * xm1 + b2 * xm2 - a2 * ym2;
        float yt = t - a1 * ym1;
        xm2 = xm1; xm1 = xt;
        ym2 = ym1; ym1 = yt;
        return yt;
    };

    issue_loads(0, 0);

    for (int k = 0; k < ITERS; ++k) {
        const int bufi = k & 1;
        if (k + 1 < ITERS) issue_loads(k + 1, bufi ^ 1);

        // vmcnt retires in issue order. Outstanding (oldest->newest):
        //   loads_k (8) [, stores_{k-1} (8) if k-1>=SKIP] [, loads_{k+1} (8)]
        // Drain exactly loads_k:
        if (k > SKIP && k + 1 < ITERS) {
            asm volatile("s_waitcnt vmcnt(16)" ::: "memory");
        } else {
            asm volatile("s_waitcnt vmcnt(8)" ::: "memory");
        }
        __builtin_amdgcn_sched_barrier(0);

        // private 128 B from LDS (swizzled slots)
        f4 r[8];
#pragma unroll
        for (int v = 0; v < 8; ++v)
            r[v] = inb[bufi][(lane << 3) + (v ^ (lane & 7))];

        if (firstWave && lane == 0 && k < SKIP) {
            // row-first chunk: warm-up region is pre-row -> true zero state
#pragma unroll
            for (int v = 0; v < 8; ++v) r[v] = (f4)(0.f);
        }

        f4 o[8];
#pragma unroll
        for (int v = 0; v < 8; ++v) {
            o[v].x = step(r[v].x);
            o[v].y = step(r[v].y);
            o[v].z = step(r[v].z);
            o[v].w = step(r[v].w);
        }

        if (k >= SKIP) {
            // swizzled write, linear coop read -> coalesced global store
#pragma unroll
            for (int v = 0; v < 8; ++v)
                outb[(lane << 3) + (v ^ (lane & 7))] = o[v];
            f4 t[8];
#pragma unroll
            for (int j = 0; j < 8; ++j)
                t[j] = outb[(j << 6) + lane];
            const int obase = waveVecBase + 8 * k + laneOff;
#pragma unroll
            for (int j = 0; j < 8; ++j)
                yv[obase + j * (8 * STRIDEV)] = t[j];
        }
    }
}

extern "C" void kernel_launch(void* const* d_in, const int* in_sizes, int n_in,
                              void* d_out, int out_size, void* d_ws, size_t ws_size,
                              hipStream_t stream) {
    const float* x  = (const float*)d_in[0];
    const float* ff = (const float*)d_in[1];
    const float* fq = (const float*)d_in[2];
    const int*   sr = (const int*)d_in[3];
    float* out = (float*)d_out;

    const int grid  = (B_ROWS * CPR) / 64;   // 2048 waves, 1 wave per block
    const int block = 64;
    hp_biquad<<<grid, block, 0, stream>>>(x, ff, fq, sr, out);
}

// Round 9
// 51.311 us; speedup vs baseline: 1.0933x; 1.0933x over previous
//
#include <hip/hip_runtime.h>
#include <math.h>

// LearnableHighpass biquad, B=64, T=524288, fp32.
// Chunked-parallel IIR (128-sample zero-state warm-up, pole^128 ~ 3e-7).
// R9 = R7 (LT=512, LDS wave-local transpose, coalesced global access)
// with prefetch distance 1 -> 3 (4 in-buffers, 40 KB LDS, still 4 blocks/CU
// = the grid cap): loads for stage k are issued 3 stages (~1000+ cy) ahead,
// covering the ~900 cy loaded HBM latency that R7's 1-stage distance (~350
// cy) left exposed (R7 profile: 2.5 TB/s, VALUBusy 8%, occ 9% = pure
// vmcnt-stall). R8 lesson: LT=256 regressed (no occupancy gain, FETCH +20%).

typedef float f4 __attribute__((ext_vector_type(4)));

namespace {
constexpr int T_LEN = 524288;
constexpr int B_ROWS = 64;
constexpr int LT = 512;                 // samples per chunk (per lane)
constexpr int WU = 128;                 // warm-up samples
constexpr int CPR = T_LEN / LT;         // 1024 chunks per row
constexpr int NV = T_LEN / 4;           // 131072 f4 vectors per row
constexpr int STRIDEV = LT / 4;         // 128 vectors chunk stride
constexpr int ITERS = (WU + LT) / 32;   // 20 stages of 32 samples
constexpr int SKIP = WU / 32;           // 4 warm-up stages (no store)
}

using gfp = const float __attribute__((address_space(1)))*;
using lfp = float __attribute__((address_space(3)))*;

__global__ __launch_bounds__(64) void hp_biquad(
    const float* __restrict__ x,
    const float* __restrict__ ffreq,
    const float* __restrict__ fqv,
    const int*  __restrict__ srv,
    float* __restrict__ y)
{
    // in: 4-deep ring (4 x 8 KB), out: 8 KB  -> 40 KB/block
    __shared__ f4 inb[4][512];
    __shared__ f4 outb[512];

    const float fsr   = (float)srv[0];
    const float w0    = 6.28318530717958647692f * ffreq[0] / fsr;
    const float sw    = sinf(w0);
    const float cw    = cosf(w0);
    const float alpha = sw / (2.0f * fqv[0]);
    const float ia0   = 1.0f / (1.0f + alpha);
    const float b0 = 0.5f * (1.0f + cw) * ia0;
    const float b1 = -(1.0f + cw) * ia0;
    const float b2 = b0;
    const float a1 = -2.0f * cw * ia0;
    const float a2 = (1.0f - alpha) * ia0;

    const int lane = threadIdx.x;               // 0..63 == chunk-lane
    const int wv   = blockIdx.x;                // wave id, 0..1023
    const int c0   = wv * 64;                   // first chunk of this wave
    const int row  = c0 / CPR;
    const int c0r  = c0 & (CPR - 1);
    const bool firstWave  = (c0r == 0);
    const int rowBaseVec  = row * NV;
    const int waveVecBase = rowBaseVec + c0r * STRIDEV - WU / 4;

    // coop call j, lane m covers chunk-lane L = 8j + (m>>3), vector
    // V = (m&7) ^ ((m>>3)&7); 8 lanes cover one contiguous 128 B segment.
    // LDS slot j*64+m holds that vector (linear dst, global_load_lds rule);
    // lane l's private vector v sits in slot (l<<3) + (v ^ (l&7)).
    const int vstar   = (lane & 7) ^ ((lane >> 3) & 7);
    const int laneOff = (lane >> 3) * STRIDEV + vstar;

    const f4* __restrict__ xv = (const f4*)x;
    f4* __restrict__ yv       = (f4*)y;

    auto issue_loads = [&](int k) {
        const int bufi  = k & 3;
        const int base  = waveVecBase + 8 * k + laneOff;
        const bool clmp = firstWave && (k < SKIP);   // wave-uniform
#pragma unroll
        for (int j = 0; j < 8; ++j) {
            int idx = base + j * (8 * STRIDEV);
            if (clmp) idx = idx < rowBaseVec ? rowBaseVec : idx;  // zeroed later
            __builtin_amdgcn_global_load_lds(
                (gfp)(const float*)(xv + idx),
                (lfp)(float*)(&inb[bufi][j * 64]), 16, 0, 0);
        }
    };

    float xm1 = 0.f, xm2 = 0.f, ym1 = 0.f, ym2 = 0.f;
    auto step = [&](float xt) -> float {
        float t  = b0 * xt + b1 * xm1 + b2 * xm2 - a2 * ym2;
        float yt = t - a1 * ym1;
        xm2 = xm1; xm1 = xt;
        ym2 = ym1; ym1 = yt;
        return yt;
    };

    issue_loads(0);
    issue_loads(1);
    issue_loads(2);

    for (int k = 0; k < ITERS; ++k) {
        if (k + 3 < ITERS) issue_loads(k + 3);

        // vmcnt retires in issue order; drain exactly loads_k.
        // Newer outstanding = 8*min(3, ITERS-1-k) loads + 8*#{j in
        // {k-1,k-2,k-3}: j>=SKIP} stores.  (ITERS=20, SKIP=4)
        if (k >= 7 && k <= 16) {
            asm volatile("s_waitcnt vmcnt(48)" ::: "memory");
        } else if (k == 6 || k == 17) {
            asm volatile("s_waitcnt vmcnt(40)" ::: "memory");
        } else if (k == 5 || k == 18) {
            asm volatile("s_waitcnt vmcnt(32)" ::: "memory");
        } else {   // k in {0..4, 19}
            asm volatile("s_waitcnt vmcnt(24)" ::: "memory");
        }
        __builtin_amdgcn_sched_barrier(0);

        // private 128 B from LDS (swizzled slots)
        const int bufi = k & 3;
        f4 r[8];
#pragma unroll
        for (int v = 0; v < 8; ++v)
            r[v] = inb[bufi][(lane << 3) + (v ^ (lane & 7))];

        if (firstWave && lane == 0 && k < SKIP) {
            // row-first chunk: warm-up region is pre-row -> true zero state
#pragma unroll
            for (int v = 0; v < 8; ++v) r[v] = (f4)(0.f);
        }

        f4 o[8];
#pragma unroll
        for (int v = 0; v < 8; ++v) {
            o[v].x = step(r[v].x);
            o[v].y = step(r[v].y);
            o[v].z = step(r[v].z);
            o[v].w = step(r[v].w);
        }

        if (k >= SKIP) {
            // swizzled write, linear coop read -> coalesced global store
#pragma unroll
            for (int v = 0; v < 8; ++v)
                outb[(lane << 3) + (v ^ (lane & 7))] = o[v];
            f4 t[8];
#pragma unroll
            for (int j = 0; j < 8; ++j)
                t[j] = outb[(j << 6) + lane];
            const int obase = waveVecBase + 8 * k + laneOff;
#pragma unroll
            for (int j = 0; j < 8; ++j)
                yv[obase + j * (8 * STRIDEV)] = t[j];
        }
    }
}

extern "C" void kernel_launch(void* const* d_in, const int* in_sizes, int n_in,
                              void* d_out, int out_size, void* d_ws, size_t ws_size,
                              hipStream_t stream) {
    const float* x  = (const float*)d_in[0];
    const float* ff = (const float*)d_in[1];
    const float* fq = (const float*)d_in[2];
    const int*   sr = (const int*)d_in[3];
    float* out = (float*)d_out;

    const int grid  = (B_ROWS * CPR) / 64;   // 1024 waves, 1 wave per block
    const int block = 64;
    hp_biquad<<<grid, block, 0, stream>>>(x, ff, fq, sr, out);
}

// Round 10
// 49.091 us; speedup vs baseline: 1.1427x; 1.0452x over previous
//
#include <hip/hip_runtime.h>
#include <math.h>

// LearnableHighpass biquad, B=64, T=524288, fp32.
// Chunked-parallel IIR (128-sample zero-state warm-up, pole^128 ~ 3e-7).
// R10 = R7/R9 structure with stage window 128B -> 256B per chunk (GV=16):
//   each coop global instr = 4 x 256B segments (16 lanes contiguous);
//   DRAM sees pairs of consecutive lines per chunk per stage (2x row
//   locality, half the requests) — attacking the stride-16-line pattern
//   that capped HBM at ~2.6 TB/s cold (R6/R8/R9 ruled out ILP/TLP/depth).
// Out-staging aliased into the retired in-buffer: LDS 2x16KB = 32 KB.
// Coop mapping (instr j, lane m): L = 4j+(m>>4), v = (m&15)^(m>>4)^(4(j&1)),
//   slot = 64j+m = L*16 + (v^(L&7)); lane l's private vec v at l*16+(v^(l&7)).

typedef float f4 __attribute__((ext_vector_type(4)));

namespace {
constexpr int T_LEN = 524288;
constexpr int B_ROWS = 64;
constexpr int LT = 512;                 // samples per chunk (per lane)
constexpr int WU = 128;                 // warm-up samples
constexpr int CPR = T_LEN / LT;         // 1024 chunks per row
constexpr int NV = T_LEN / 4;           // 131072 f4 vectors per row
constexpr int STRIDEV = LT / 4;         // 128 vectors chunk stride
constexpr int GV = 16;                  // f4 vectors per stage (256 B / lane)
constexpr int ITERS = (WU + LT) / (4 * GV);  // 10 stages
constexpr int SKIP = WU / (4 * GV);          // 2 warm-up stages (no store)
}

using gfp = const float __attribute__((address_space(1)))*;
using lfp = float __attribute__((address_space(3)))*;

__global__ __launch_bounds__(64) void hp_biquad(
    const float* __restrict__ x,
    const float* __restrict__ ffreq,
    const float* __restrict__ fqv,
    const int*  __restrict__ srv,
    float* __restrict__ y)
{
    // double-buffered in (2 x 64 chunks x 16 vec x 16 B = 2 x 16 KB);
    // out staging reuses the in-buffer being consumed.
    __shared__ f4 inb[2][1024];

    const float fsr   = (float)srv[0];
    const float w0    = 6.28318530717958647692f * ffreq[0] / fsr;
    const float sw    = sinf(w0);
    const float cw    = cosf(w0);
    const float alpha = sw / (2.0f * fqv[0]);
    const float ia0   = 1.0f / (1.0f + alpha);
    const float b0 = 0.5f * (1.0f + cw) * ia0;
    const float b1 = -(1.0f + cw) * ia0;
    const float b2 = b0;
    const float a1 = -2.0f * cw * ia0;
    const float a2 = (1.0f - alpha) * ia0;

    const int lane = threadIdx.x;               // 0..63
    const int wv   = blockIdx.x;                // wave id, 0..1023
    const int c0   = wv * 64;
    const int row  = c0 / CPR;
    const int c0r  = c0 & (CPR - 1);
    const bool firstWave  = (c0r == 0);
    const int rowBaseVec  = row * NV;
    const int waveVecBase = rowBaseVec + c0r * STRIDEV - WU / 4;

    // per-lane coop constants
    const int sub = (lane >> 4) * STRIDEV;            // chunk-sub-offset
    const int ve  = (lane & 15) ^ (lane >> 4);        // swizzled vec, j even
    const int laneOffE = sub + ve;
    const int laneOffO = sub + (ve ^ 4);              // j odd

    const f4* __restrict__ xv = (const f4*)x;
    f4* __restrict__ yv       = (f4*)y;

    auto issue_loads = [&](int k, int bufi) {
        const int base  = waveVecBase + GV * k;
        const bool clmp = firstWave && (k < SKIP);    // wave-uniform
#pragma unroll
        for (int j = 0; j < 16; ++j) {
            int idx = base + j * (4 * STRIDEV) + ((j & 1) ? laneOffO : laneOffE);
            if (clmp) idx = idx < rowBaseVec ? rowBaseVec : idx;  // zeroed later
            __builtin_amdgcn_global_load_lds(
                (gfp)(const float*)(xv + idx),
                (lfp)(float*)(&inb[bufi][j * 64]), 16, 0, 0);
        }
    };

    float xm1 = 0.f, xm2 = 0.f, ym1 = 0.f, ym2 = 0.f;
    auto step = [&](float xt) -> float {
        float t  = b0 * xt + b1 * xm1 + b2 * xm2 - a2 * ym2;
        float yt = t - a1 * ym1;
        xm2 = xm1; xm1 = xt;
        ym2 = ym1; ym1 = yt;
        return yt;
    };

    issue_loads(0, 0);

    for (int k = 0; k < ITERS; ++k) {
        const int bufi = k & 1;
        if (k + 1 < ITERS) issue_loads(k + 1, bufi ^ 1);

        // vmcnt retires in issue order; drain exactly loads_k (16 ops).
        // newer = 16*[k+1<ITERS] + 16*[k-1>=SKIP]  (ITERS=10, SKIP=2)
        if (k >= 3 && k <= 8) {
            asm volatile("s_waitcnt vmcnt(32)" ::: "memory");
        } else {
            asm volatile("s_waitcnt vmcnt(16)" ::: "memory");
        }
        __builtin_amdgcn_sched_barrier(0);

        // private 256 B from LDS (swizzled slots)
        f4 r[GV];
#pragma unroll
        for (int v = 0; v < GV; ++v)
            r[v] = inb[bufi][(lane << 4) + (v ^ (lane & 7))];

        if (firstWave && lane == 0 && k < SKIP) {
            // row-first chunk: warm-up region is pre-row -> true zero state
#pragma unroll
            for (int v = 0; v < GV; ++v) r[v] = (f4)(0.f);
        }

        f4 o[GV];
#pragma unroll
        for (int v = 0; v < GV; ++v) {
            o[v].x = step(r[v].x);
            o[v].y = step(r[v].y);
            o[v].z = step(r[v].z);
            o[v].w = step(r[v].w);
        }

        if (k >= SKIP) {
            // swizzled write back into the consumed buffer, linear coop
            // read, coalesced 256B-segment global store
#pragma unroll
            for (int v = 0; v < GV; ++v)
                inb[bufi][(lane << 4) + (v ^ (lane & 7))] = o[v];
            f4 t[16];
#pragma unroll
            for (int j = 0; j < 16; ++j)
                t[j] = inb[bufi][(j << 6) + lane];
            const int obase = waveVecBase + GV * k;
#pragma unroll
            for (int j = 0; j < 16; ++j)
                yv[obase + j * (4 * STRIDEV) + ((j & 1) ? laneOffO : laneOffE)] = t[j];
        }
    }
}

extern "C" void kernel_launch(void* const* d_in, const int* in_sizes, int n_in,
                              void* d_out, int out_size, void* d_ws, size_t ws_size,
                              hipStream_t stream) {
    const float* x  = (const float*)d_in[0];
    const float* ff = (const float*)d_in[1];
    const float* fq = (const float*)d_in[2];
    const int*   sr = (const int*)d_in[3];
    float* out = (float*)d_out;

    const int grid  = (B_ROWS * CPR) / 64;   // 1024 waves, 1 wave per block
    const int block = 64;
    hp_biquad<<<grid, block, 0, stream>>>(x, ff, fq, sr, out);
}

// Round 11
// 45.930 us; speedup vs baseline: 1.2214x; 1.0688x over previous
//
#include <hip/hip_runtime.h>
#include <math.h>

// LearnableHighpass biquad, B=64, T=524288, fp32.
// Chunked-parallel IIR (zero-state warm-up; pole radius 0.888).
// R11 = R10 (GV=16: 256B/chunk stage windows, coalesced LDS-transposed
// global access, counted-vmcnt pipeline, out-staging aliased into the
// consumed in-buffer) +
//  - WU 128 -> 64: rho^64 ~ 5e-4 (abs err ~1.5e-3, threshold 1.075e-1);
//    logical reads 160 -> 144 MB, ITERS 10 -> 9.
//  - NONTEMPORAL coalesced stores: y is write-once; stores are now full
//    256B segments (complete lines, unlike R4's scattered 16B pieces), so
//    nt writes exact traffic while keeping x L3-resident across replays.

typedef float f4 __attribute__((ext_vector_type(4)));

namespace {
constexpr int T_LEN = 524288;
constexpr int B_ROWS = 64;
constexpr int LT = 512;                 // samples per chunk (per lane)
constexpr int WU = 64;                  // warm-up samples
constexpr int CPR = T_LEN / LT;         // 1024 chunks per row
constexpr int NV = T_LEN / 4;           // 131072 f4 vectors per row
constexpr int STRIDEV = LT / 4;         // 128 vectors chunk stride
constexpr int GV = 16;                  // f4 vectors per stage (256 B / lane)
constexpr int ITERS = (WU + LT) / (4 * GV);  // 9 stages
constexpr int SKIP = WU / (4 * GV);          // 1 warm-up stage (no store)
}

using gfp = const float __attribute__((address_space(1)))*;
using lfp = float __attribute__((address_space(3)))*;

__global__ __launch_bounds__(64) void hp_biquad(
    const float* __restrict__ x,
    const float* __restrict__ ffreq,
    const float* __restrict__ fqv,
    const int*  __restrict__ srv,
    float* __restrict__ y)
{
    // double-buffered in (2 x 64 chunks x 16 vec x 16 B = 2 x 16 KB);
    // out staging reuses the in-buffer being consumed.
    __shared__ f4 inb[2][1024];

    const float fsr   = (float)srv[0];
    const float w0    = 6.28318530717958647692f * ffreq[0] / fsr;
    const float sw    = sinf(w0);
    const float cw    = cosf(w0);
    const float alpha = sw / (2.0f * fqv[0]);
    const float ia0   = 1.0f / (1.0f + alpha);
    const float b0 = 0.5f * (1.0f + cw) * ia0;
    const float b1 = -(1.0f + cw) * ia0;
    const float b2 = b0;
    const float a1 = -2.0f * cw * ia0;
    const float a2 = (1.0f - alpha) * ia0;

    const int lane = threadIdx.x;               // 0..63
    const int wv   = blockIdx.x;                // wave id, 0..1023
    const int c0   = wv * 64;
    const int row  = c0 / CPR;
    const int c0r  = c0 & (CPR - 1);
    const bool firstWave  = (c0r == 0);
    const int rowBaseVec  = row * NV;
    const int waveVecBase = rowBaseVec + c0r * STRIDEV - WU / 4;

    // coop mapping (instr j, lane m): chunk L = 4j+(m>>4),
    // vec v = (m&15)^(m>>4)^(4(j&1)); slot 64j+m = L*16 + (v^(L&7)).
    // lane l's private vec v sits at slot l*16 + (v^(l&7)).
    const int sub = (lane >> 4) * STRIDEV;            // chunk-sub-offset
    const int ve  = (lane & 15) ^ (lane >> 4);        // swizzled vec, j even
    const int laneOffE = sub + ve;
    const int laneOffO = sub + (ve ^ 4);              // j odd

    const f4* __restrict__ xv = (const f4*)x;
    f4* __restrict__ yv       = (f4*)y;

    auto issue_loads = [&](int k, int bufi) {
        const int base  = waveVecBase + GV * k;
        const bool clmp = firstWave && (k < SKIP);    // wave-uniform
#pragma unroll
        for (int j = 0; j < 16; ++j) {
            int idx = base + j * (4 * STRIDEV) + ((j & 1) ? laneOffO : laneOffE);
            if (clmp) idx = idx < rowBaseVec ? rowBaseVec : idx;  // zeroed later
            __builtin_amdgcn_global_load_lds(
                (gfp)(const float*)(xv + idx),
                (lfp)(float*)(&inb[bufi][j * 64]), 16, 0, 0);
        }
    };

    float xm1 = 0.f, xm2 = 0.f, ym1 = 0.f, ym2 = 0.f;
    auto step = [&](float xt) -> float {
        float t  = b0 * xt + b1 * xm1 + b2 * xm2 - a2 * ym2;
        float yt = t - a1 * ym1;
        xm2 = xm1; xm1 = xt;
        ym2 = ym1; ym1 = yt;
        return yt;
    };

    issue_loads(0, 0);

    for (int k = 0; k < ITERS; ++k) {
        const int bufi = k & 1;
        if (k + 1 < ITERS) issue_loads(k + 1, bufi ^ 1);

        // vmcnt retires in issue order; drain exactly loads_k (16 ops).
        // newer = 16*[k+1<ITERS] + 16*[k-1>=SKIP]   (ITERS=9, SKIP=1)
        if (k >= SKIP + 1 && k + 1 < ITERS) {
            asm volatile("s_waitcnt vmcnt(32)" ::: "memory");
        } else {
            asm volatile("s_waitcnt vmcnt(16)" ::: "memory");
        }
        __builtin_amdgcn_sched_barrier(0);

        // private 256 B from LDS (swizzled slots)
        f4 r[GV];
#pragma unroll
        for (int v = 0; v < GV; ++v)
            r[v] = inb[bufi][(lane << 4) + (v ^ (lane & 7))];

        if (firstWave && lane == 0 && k < SKIP) {
            // row-first chunk: warm-up region is pre-row -> true zero state
#pragma unroll
            for (int v = 0; v < GV; ++v) r[v] = (f4)(0.f);
        }

        f4 o[GV];
#pragma unroll
        for (int v = 0; v < GV; ++v) {
            o[v].x = step(r[v].x);
            o[v].y = step(r[v].y);
            o[v].z = step(r[v].z);
            o[v].w = step(r[v].w);
        }

        if (k >= SKIP) {
            // swizzled write back into the consumed buffer, linear coop
            // read, coalesced nontemporal 256B-segment global store
#pragma unroll
            for (int v = 0; v < GV; ++v)
                inb[bufi][(lane << 4) + (v ^ (lane & 7))] = o[v];
            f4 t[16];
#pragma unroll
            for (int j = 0; j < 16; ++j)
                t[j] = inb[bufi][(j << 6) + lane];
            const int obase = waveVecBase + GV * k;
#pragma unroll
            for (int j = 0; j < 16; ++j)
                __builtin_nontemporal_store(
                    t[j],
                    &yv[obase + j * (4 * STRIDEV) + ((j & 1) ? laneOffO : laneOffE)]);
        }
    }
}

extern "C" void kernel_launch(void* const* d_in, const int* in_sizes, int n_in,
                              void* d_out, int out_size, void* d_ws, size_t ws_size,
                              hipStream_t stream) {
    const float* x  = (const float*)d_in[0];
    const float* ff = (const float*)d_in[1];
    const float* fq = (const float*)d_in[2];
    const int*   sr = (const int*)d_in[3];
    float* out = (float*)d_out;

    const int grid  = (B_ROWS * CPR) / 64;   // 1024 waves, 1 wave per block
    const int block = 64;
    hp_biquad<<<grid, block, 0, stream>>>(x, ff, fq, sr, out);
}